// Round 5
// baseline (499.878 us; speedup 1.0000x reference)
//
#include <hip/hip_runtime.h>

typedef unsigned int uint32;
typedef unsigned long long uint64;

#define BLOCK 256
#define WAVES 4
#define WROWS 1024              // rows per wave (contiguous sub-chunk)
#define CHUNK (WAVES * WROWS)   // 4096 rows per block
#define SCORE_THR 0.35f

// flag word: [63:62] state (0=X invalid, 1=A aggregate, 2=P inclusive prefix)
//            [45:23] v1 (23 bits), [22:0] v0 (23 bits).  R <= 4M fits in 23 bits.
__device__ __forceinline__ uint64 pack_flag(uint64 st, uint32 v0, uint32 v1) {
    return (st << 62) | ((uint64)(v1 & 0x7FFFFFu) << 23) | (uint64)(v0 & 0x7FFFFFu);
}

__global__ void init_kernel(uint64* __restrict__ flags, uint32* __restrict__ ticket, int NB) {
    int i = blockIdx.x * blockDim.x + threadIdx.x;
    if (i == 0) *ticket = 0u;
    int stride = gridDim.x * blockDim.x;
    for (int j = i; j < NB; j += stride) flags[j] = 0ull;
}

// wave-cooperative zero of n floats at p (handles alignment head/tail)
__device__ __forceinline__ void wave_zero(float* p, long long n, int lane) {
    if (n <= 0) return;
    long long head = (long long)((4 - (((size_t)p >> 2) & 3)) & 3);
    if (head > n) head = n;
    if (lane < head) p[lane] = 0.0f;
    long long n4 = (n - head) >> 2;
    float4* b = (float4*)(p + head);
    float4 z = make_float4(0.f, 0.f, 0.f, 0.f);
    for (long long k = lane; k < n4; k += 64) b[k] = z;
    long long done = head + (n4 << 2);
    long long rem = n - done;
    if (lane < rem) p[done + lane] = 0.0f;
}

__global__ __launch_bounds__(BLOCK, 4) void fused_kernel(
        const float* __restrict__ det,
        float* __restrict__ rois, float* __restrict__ roisf,
        uint64* __restrict__ flags, uint32* __restrict__ ticket,
        float* __restrict__ out_n, int R, int NB) {
    const int tid  = threadIdx.x;
    const int wave = tid >> 6;
    const int lane = tid & 63;
    const uint64 ltmask = (1ull << lane) - 1ull;

    __shared__ uint32 s_vid;
    __shared__ uint32 wa0[WAVES], wa1[WAVES];
    __shared__ uint32 s_pre0, s_pre1;

    // ---- ticket: vid == scheduling order => spinning on vid' < vid is deadlock-free
    if (tid == 0) s_vid = atomicAdd(ticket, 1u);
    __syncthreads();
    const uint32 vid = s_vid;

    const long long gstart = (long long)vid * CHUNK + (long long)wave * WROWS;
    int wcnt = 0;
    if (gstart < (long long)R) {
        long long rem = (long long)R - gstart;
        wcnt = (rem >= (long long)WROWS) ? WROWS : (int)rem;
    }
    const bool full = (wcnt == WROWS);
    const float4* d4 = ((const float4*)det) + ((gstart * 6) >> 2);   // gstart % 1024 == 0

    // ---- Phase 1: count own sub-chunk (the only HBM read) ----
    uint32 a0 = 0, a1 = 0;
    if (full) {
        for (int it = 0; it < WROWS / 128; ++it) {
            const float4* p = d4 + it * 192 + 3 * lane;
            float4 f0 = p[0], f1 = p[1], f2 = p[2];
            bool mA1 = (f1.y >= SCORE_THR);
            bool mA0 = mA1 && (f0.x == 0.0f);
            bool mB1 = (f2.w >= SCORE_THR);
            bool mB0 = mB1 && (f1.z == 0.0f);
            a1 += (mA1 ? 1u : 0u) + (mB1 ? 1u : 0u);
            a0 += (mA0 ? 1u : 0u) + (mB0 ? 1u : 0u);
        }
    } else if (wcnt > 0) {
        for (int i = lane; i < wcnt; i += 64) {
            const float* q = det + (gstart + i) * 6;
            float c = q[0], s = q[5];
            bool m1 = (s >= SCORE_THR);
            bool m0 = m1 && (c == 0.0f);
            a1 += m1 ? 1u : 0u;
            a0 += m0 ? 1u : 0u;
        }
    }
    for (int off = 32; off > 0; off >>= 1) {
        a0 += __shfl_down(a0, off, 64);
        a1 += __shfl_down(a1, off, 64);
    }
    if (lane == 0) { wa0[wave] = a0; wa1[wave] = a1; }
    __syncthreads();

    // ---- Phase 2: publish aggregate, decoupled lookback (wave 0 only) ----
    if (wave == 0) {
        const uint32 b0 = wa0[0] + wa0[1] + wa0[2] + wa0[3];
        const uint32 b1 = wa1[0] + wa1[1] + wa1[2] + wa1[3];
        if (lane == 0 && vid > 0)
            __hip_atomic_store(&flags[vid], pack_flag(1ull, b0, b1),
                               __ATOMIC_RELEASE, __HIP_MEMORY_SCOPE_AGENT);
        uint32 r0 = 0, r1 = 0;                 // exclusive prefix, valid at lane 0
        if (vid > 0) {
            int j = (int)vid;                  // window is [j-64, j)
            bool done = false;
            while (!done && j > 0) {
                int idx = j - 64 + lane;
                bool advanced = false;
                while (!advanced) {
                    uint64 f = 0; uint32 st = 2u;          // idx<0 => virtual P with value 0
                    if (idx >= 0) {
                        f = __hip_atomic_load(&flags[idx],
                                              __ATOMIC_ACQUIRE, __HIP_MEMORY_SCOPE_AGENT);
                        st = (uint32)(f >> 62);
                    }
                    uint64 pm = __ballot(st == 2u);
                    uint64 xm = __ballot(st == 0u);
                    if (pm != 0ull) {
                        int L = 63 - (int)__clzll(pm);     // highest lane with P
                        if ((xm & ((~0ull) << L)) == 0ull) {
                            // lane L: inclusive prefix; lanes > L: aggregates
                            uint32 c0 = (lane >= L) ? (uint32)(f & 0x7FFFFFull) : 0u;
                            uint32 c1 = (lane >= L) ? (uint32)((f >> 23) & 0x7FFFFFull) : 0u;
                            for (int off = 32; off > 0; off >>= 1) {
                                c0 += __shfl_down(c0, off, 64);
                                c1 += __shfl_down(c1, off, 64);
                            }
                            r0 += c0; r1 += c1;
                            done = true; advanced = true;
                        }
                    } else if (xm == 0ull) {
                        // whole window is A: accumulate and slide down
                        uint32 c0 = (uint32)(f & 0x7FFFFFull);
                        uint32 c1 = (uint32)((f >> 23) & 0x7FFFFFull);
                        for (int off = 32; off > 0; off >>= 1) {
                            c0 += __shfl_down(c0, off, 64);
                            c1 += __shfl_down(c1, off, 64);
                        }
                        r0 += c0; r1 += c1;
                        j -= 64; advanced = true;
                    }
                    if (!advanced) __builtin_amdgcn_s_sleep(2);
                }
            }
        }
        if (lane == 0) {
            __hip_atomic_store(&flags[vid], pack_flag(2ull, r0 + b0, r1 + b1),
                               __ATOMIC_RELEASE, __HIP_MEMORY_SCOPE_AGENT);
            s_pre0 = r0; s_pre1 = r1;
            if (vid == (uint32)(NB - 1)) {     // last chunk knows the grand totals
                out_n[0] = (float)(r0 + b0);
                out_n[1] = (float)(r1 + b1);
            }
        }
    }
    __syncthreads();

    // per-wave global write bases (block prefix + lower waves' aggregates)
    uint32 run0 = s_pre0, run1 = s_pre1;
    for (int w = 0; w < wave; ++w) { run0 += wa0[w]; run1 += wa1[w]; }
    const uint32 wstart0 = run0, wstart1 = run1;

    // ---- Phase 3: re-read (L2/L3-hot) + direct stable scatter, no barriers ----
    if (full) {
        for (int it = 0; it < WROWS / 128; ++it) {
            const float4* p = d4 + it * 192 + 3 * lane;
            float4 f0 = p[0], f1 = p[1], f2 = p[2];
            // row A = {f0.x,f0.y,f0.z,f0.w,f1.x,f1.y}, row B = {f1.z,f1.w,f2.x,f2.y,f2.z,f2.w}
            bool mA1 = (f1.y >= SCORE_THR);
            bool mA0 = mA1 && (f0.x == 0.0f);
            bool mB1 = (f2.w >= SCORE_THR);
            bool mB0 = mB1 && (f1.z == 0.0f);
            uint64 bA0 = __ballot(mA0), bA1 = __ballot(mA1);
            uint64 bB0 = __ballot(mB0), bB1 = __ballot(mB1);
            uint32 lA0 = (uint32)(__popcll(bA0 & ltmask) + __popcll(bB0 & ltmask));
            uint32 lB0 = lA0 + (mA0 ? 1u : 0u);
            uint32 lA1 = (uint32)(__popcll(bA1 & ltmask) + __popcll(bB1 & ltmask));
            uint32 lB1 = lA1 + (mA1 ? 1u : 0u);
            if (mA0) {
                float* q = rois + (long long)(run0 + lA0) * 5;
                q[0] = 0.0f; q[1] = f0.y; q[2] = f0.z; q[3] = f0.w; q[4] = f1.x;
            }
            if (mB0) {
                float* q = rois + (long long)(run0 + lB0) * 5;
                q[0] = 0.0f; q[1] = f1.w; q[2] = f2.x; q[3] = f2.y; q[4] = f2.z;
            }
            if (mA1) {
                float* q = roisf + (long long)(run1 + lA1) * 6;
                q[0] = f0.x; q[1] = f0.y; q[2] = f0.z; q[3] = f0.w; q[4] = f1.x; q[5] = f1.y;
            }
            if (mB1) {
                float* q = roisf + (long long)(run1 + lB1) * 6;
                q[0] = f1.z; q[1] = f1.w; q[2] = f2.x; q[3] = f2.y; q[4] = f2.z; q[5] = f2.w;
            }
            run0 += (uint32)(__popcll(bA0) + __popcll(bB0));
            run1 += (uint32)(__popcll(bA1) + __popcll(bB1));
        }
    } else if (wcnt > 0) {
        for (int it = 0; it * 64 < wcnt; ++it) {
            int i = it * 64 + lane;
            bool m0 = false, m1 = false;
            float d0 = 0.f, d1 = 0.f, d2 = 0.f, d3 = 0.f, d4v = 0.f, d5 = 0.f;
            if (i < wcnt) {
                const float* q = det + (gstart + i) * 6;
                d0 = q[0]; d1 = q[1]; d2 = q[2]; d3 = q[3]; d4v = q[4]; d5 = q[5];
                m1 = (d5 >= SCORE_THR);
                m0 = m1 && (d0 == 0.0f);
            }
            uint64 b0m = __ballot(m0), b1m = __ballot(m1);
            if (m0) {
                float* q = rois + (long long)(run0 + (uint32)__popcll(b0m & ltmask)) * 5;
                q[0] = 0.0f; q[1] = d1; q[2] = d2; q[3] = d3; q[4] = d4v;
            }
            if (m1) {
                float* q = roisf + (long long)(run1 + (uint32)__popcll(b1m & ltmask)) * 6;
                q[0] = d0; q[1] = d1; q[2] = d2; q[3] = d3; q[4] = d4v; q[5] = d5;
            }
            run0 += (uint32)__popcll(b0m);
            run1 += (uint32)__popcll(b1m);
        }
    }

    // ---- Phase 4: per-wave zero slice, assigned from the TOP of the array ----
    // wave frees (wcnt - g) slots; cumulative freed before it = gstart - wstart.
    // zero rows [R - gstart - wcnt + wstart + g, R - gstart + wstart); disjoint,
    // union over all waves == [tot, R). Needs no grand total.
    {
        uint32 g0 = wa0[wave];
        long long z0s = (long long)R - gstart - wcnt + (long long)wstart0 + g0;
        long long z0e = (long long)R - gstart + (long long)wstart0;
        wave_zero(rois + z0s * 5, (z0e - z0s) * 5, lane);
        uint32 g1 = wa1[wave];
        long long z1s = (long long)R - gstart - wcnt + (long long)wstart1 + g1;
        long long z1e = (long long)R - gstart + (long long)wstart1;
        wave_zero(roisf + z1s * 6, (z1e - z1s) * 6, lane);
    }
}

extern "C" void kernel_launch(void* const* d_in, const int* in_sizes, int n_in,
                              void* d_out, int out_size, void* d_ws, size_t ws_size,
                              hipStream_t stream) {
    const float* det = (const float*)d_in[0];
    float* out = (float*)d_out;
    int R = in_sizes[0] / 6;
    int NB = (R + CHUNK - 1) / CHUNK;
    if (NB < 1) NB = 1;

    uint64* flags  = (uint64*)d_ws;          // NB * 8 bytes
    uint32* ticket = (uint32*)(flags + NB);  // + 4 bytes

    float* rois  = out;                      // (R,5)
    float* roisf = out + (long long)R * 5;   // (R,6)
    float* nout  = out + (long long)R * 11;  // n, n_full

    int initBlocks = (NB + BLOCK - 1) / BLOCK;
    init_kernel<<<initBlocks, BLOCK, 0, stream>>>(flags, ticket, NB);
    fused_kernel<<<NB, BLOCK, 0, stream>>>(det, rois, roisf, flags, ticket, nout, R, NB);
}

// Round 6
// 271.468 us; speedup vs baseline: 1.8414x; 1.8414x over previous
//
#include <hip/hip_runtime.h>

typedef unsigned int uint32;
typedef unsigned long long uint64;

#define BLOCK 256
#define WAVES 4
#define WROWS 1024              // rows per wave (contiguous sub-chunk)
#define CHUNK (WAVES * WROWS)   // 4096 rows per block
#define SCORE_THR 0.35f

// wave-cooperative zero of n floats at p (handles alignment head/tail)
__device__ __forceinline__ void wave_zero(float* p, long long n, int lane) {
    if (n <= 0) return;
    long long head = (long long)((4 - (((size_t)p >> 2) & 3)) & 3);
    if (head > n) head = n;
    if (lane < head) p[lane] = 0.0f;
    long long n4 = (n - head) >> 2;
    float4* b = (float4*)(p + head);
    float4 z = make_float4(0.f, 0.f, 0.f, 0.f);
    for (long long k = lane; k < n4; k += 64) b[k] = z;
    long long done = head + (n4 << 2);
    long long rem = n - done;
    if (lane < rem) p[done + lane] = 0.0f;
}

// ---------------- Kernel 1: per-WAVE mask counts, no LDS, no barriers ------
__global__ __launch_bounds__(BLOCK) void count_kernel(
        const float* __restrict__ det,
        uint32* __restrict__ c0, uint32* __restrict__ c1, int R) {
    const int wave = threadIdx.x >> 6;
    const int lane = threadIdx.x & 63;
    const int gw = blockIdx.x * WAVES + wave;        // global wave id
    const long long gstart = (long long)gw * WROWS;

    int wcnt = 0;
    if (gstart < (long long)R) {
        long long rem = (long long)R - gstart;
        wcnt = (rem >= (long long)WROWS) ? WROWS : (int)rem;
    }
    const bool full = (wcnt == WROWS);
    const float4* d4 = ((const float4*)det) + ((gstart * 6) >> 2);   // gstart % 1024 == 0

    uint32 a0 = 0, a1 = 0;
    if (full) {
        for (int it = 0; it < WROWS / 128; ++it) {
            const float4* p = d4 + it * 192 + 3 * lane;
            float4 f0 = p[0], f1 = p[1], f2 = p[2];
            bool mA1 = (f1.y >= SCORE_THR);
            bool mA0 = mA1 && (f0.x == 0.0f);
            bool mB1 = (f2.w >= SCORE_THR);
            bool mB0 = mB1 && (f1.z == 0.0f);
            a1 += (mA1 ? 1u : 0u) + (mB1 ? 1u : 0u);
            a0 += (mA0 ? 1u : 0u) + (mB0 ? 1u : 0u);
        }
    } else if (wcnt > 0) {
        for (int i = lane; i < wcnt; i += 64) {
            const float* q = det + (gstart + i) * 6;
            float c = q[0], s = q[5];
            bool m1 = (s >= SCORE_THR);
            bool m0 = m1 && (c == 0.0f);
            a1 += m1 ? 1u : 0u;
            a0 += m0 ? 1u : 0u;
        }
    }
    for (int off = 32; off > 0; off >>= 1) {
        a0 += __shfl_down(a0, off, 64);
        a1 += __shfl_down(a1, off, 64);
    }
    if (lane == 0) { c0[gw] = a0; c1[gw] = a1; }     // 0 for empty waves too
}

// ------- Kernel 2: per-wave prefix scan + direct stable scatter + zero -----
// No LDS, no __syncthreads, no atomics. Kernel boundary is the global sync.
__global__ __launch_bounds__(BLOCK) void scatter_kernel(
        const float* __restrict__ det,
        float* __restrict__ rois, float* __restrict__ roisf,
        const uint32* __restrict__ c0, const uint32* __restrict__ c1,
        float* __restrict__ out_n, int R, int NW) {
    const int wave = threadIdx.x >> 6;
    const int lane = threadIdx.x & 63;
    const uint64 ltmask = (1ull << lane) - 1ull;
    const int gw = blockIdx.x * WAVES + wave;
    const long long gstart = (long long)gw * WROWS;

    int wcnt = 0;
    if (gstart < (long long)R) {
        long long rem = (long long)R - gstart;
        wcnt = (rem >= (long long)WROWS) ? WROWS : (int)rem;
    }
    const bool full = (wcnt == WROWS);
    const float4* d4 = ((const float4*)det) + ((gstart * 6) >> 2);

    // ---- exclusive prefix over all earlier waves (coalesced, L2-hot) ----
    uint32 p0 = 0, p1 = 0;
    for (int j = lane; j < gw; j += 64) { p0 += c0[j]; p1 += c1[j]; }
    for (int off = 32; off > 0; off >>= 1) {
        p0 += __shfl_down(p0, off, 64);
        p1 += __shfl_down(p1, off, 64);
    }
    uint32 run0 = __shfl(p0, 0, 64);        // broadcast exclusive prefix
    uint32 run1 = __shfl(p1, 0, 64);
    const uint32 wstart0 = run0, wstart1 = run1;
    const uint32 g0 = c0[gw], g1 = c1[gw];  // own aggregate (uniform load)

    if (gw == NW - 1 && lane == 0) {        // last wave knows grand totals
        out_n[0] = (float)(wstart0 + g0);
        out_n[1] = (float)(wstart1 + g1);
    }

    // ---- direct stable scatter (ballot ranks), verified in fused run ----
    if (full) {
        for (int it = 0; it < WROWS / 128; ++it) {
            const float4* p = d4 + it * 192 + 3 * lane;
            float4 f0 = p[0], f1 = p[1], f2 = p[2];
            // row A = {f0.x,f0.y,f0.z,f0.w,f1.x,f1.y}, row B = {f1.z,f1.w,f2.x,f2.y,f2.z,f2.w}
            bool mA1 = (f1.y >= SCORE_THR);
            bool mA0 = mA1 && (f0.x == 0.0f);
            bool mB1 = (f2.w >= SCORE_THR);
            bool mB0 = mB1 && (f1.z == 0.0f);
            uint64 bA0 = __ballot(mA0), bA1 = __ballot(mA1);
            uint64 bB0 = __ballot(mB0), bB1 = __ballot(mB1);
            uint32 lA0 = (uint32)(__popcll(bA0 & ltmask) + __popcll(bB0 & ltmask));
            uint32 lB0 = lA0 + (mA0 ? 1u : 0u);
            uint32 lA1 = (uint32)(__popcll(bA1 & ltmask) + __popcll(bB1 & ltmask));
            uint32 lB1 = lA1 + (mA1 ? 1u : 0u);
            if (mA0) {
                float* q = rois + (long long)(run0 + lA0) * 5;
                q[0] = 0.0f; q[1] = f0.y; q[2] = f0.z; q[3] = f0.w; q[4] = f1.x;
            }
            if (mB0) {
                float* q = rois + (long long)(run0 + lB0) * 5;
                q[0] = 0.0f; q[1] = f1.w; q[2] = f2.x; q[3] = f2.y; q[4] = f2.z;
            }
            if (mA1) {
                float* q = roisf + (long long)(run1 + lA1) * 6;
                q[0] = f0.x; q[1] = f0.y; q[2] = f0.z; q[3] = f0.w; q[4] = f1.x; q[5] = f1.y;
            }
            if (mB1) {
                float* q = roisf + (long long)(run1 + lB1) * 6;
                q[0] = f1.z; q[1] = f1.w; q[2] = f2.x; q[3] = f2.y; q[4] = f2.z; q[5] = f2.w;
            }
            run0 += (uint32)(__popcll(bA0) + __popcll(bB0));
            run1 += (uint32)(__popcll(bA1) + __popcll(bB1));
        }
    } else if (wcnt > 0) {
        for (int it = 0; it * 64 < wcnt; ++it) {
            int i = it * 64 + lane;
            bool m0 = false, m1 = false;
            float d0 = 0.f, d1 = 0.f, d2 = 0.f, d3 = 0.f, d4v = 0.f, d5 = 0.f;
            if (i < wcnt) {
                const float* q = det + (gstart + i) * 6;
                d0 = q[0]; d1 = q[1]; d2 = q[2]; d3 = q[3]; d4v = q[4]; d5 = q[5];
                m1 = (d5 >= SCORE_THR);
                m0 = m1 && (d0 == 0.0f);
            }
            uint64 b0m = __ballot(m0), b1m = __ballot(m1);
            if (m0) {
                float* q = rois + (long long)(run0 + (uint32)__popcll(b0m & ltmask)) * 5;
                q[0] = 0.0f; q[1] = d1; q[2] = d2; q[3] = d3; q[4] = d4v;
            }
            if (m1) {
                float* q = roisf + (long long)(run1 + (uint32)__popcll(b1m & ltmask)) * 6;
                q[0] = d0; q[1] = d1; q[2] = d2; q[3] = d3; q[4] = d4v; q[5] = d5;
            }
            run0 += (uint32)__popcll(b0m);
            run1 += (uint32)__popcll(b1m);
        }
    }

    // ---- per-wave zero slice from the TOP of the array (verified algebra):
    // wave frees (wcnt - g) slots; freed before it = gstart - wstart.
    // zero rows [R - gstart - wcnt + wstart + g, R - gstart + wstart);
    // disjoint across waves, union == [tot, R). Empty waves get length 0.
    {
        long long z0s = (long long)R - gstart - wcnt + (long long)wstart0 + g0;
        long long z0e = (long long)R - gstart + (long long)wstart0;
        wave_zero(rois + z0s * 5, (z0e - z0s) * 5, lane);
        long long z1s = (long long)R - gstart - wcnt + (long long)wstart1 + g1;
        long long z1e = (long long)R - gstart + (long long)wstart1;
        wave_zero(roisf + z1s * 6, (z1e - z1s) * 6, lane);
    }
}

extern "C" void kernel_launch(void* const* d_in, const int* in_sizes, int n_in,
                              void* d_out, int out_size, void* d_ws, size_t ws_size,
                              hipStream_t stream) {
    const float* det = (const float*)d_in[0];
    float* out = (float*)d_out;
    int R = in_sizes[0] / 6;
    int NB = (R + CHUNK - 1) / CHUNK;
    if (NB < 1) NB = 1;
    int NW = NB * WAVES;

    uint32* ws = (uint32*)d_ws;
    uint32* c0 = ws;            // NW entries
    uint32* c1 = ws + NW;       // NW entries

    float* rois  = out;                          // (R,5)
    float* roisf = out + (long long)R * 5;       // (R,6)
    float* nout  = out + (long long)R * 11;      // n, n_full

    count_kernel<<<NB, BLOCK, 0, stream>>>(det, c0, c1, R);
    scatter_kernel<<<NB, BLOCK, 0, stream>>>(det, rois, roisf, c0, c1, nout, R, NW);
}